// Round 6
// baseline (280.505 us; speedup 1.0000x reference)
//
#include <hip/hip_runtime.h>
#include <stdint.h>

// Problem constants: b=16, f=8, n=256, N=2048, dim=512, H=8, DH=64, keys/group=257
#define ATT_SCALE 0.125f

typedef __attribute__((ext_vector_type(8))) short bhalf8;       // 8 bf16 = 4 VGPR (MFMA A/B frag)
typedef __attribute__((ext_vector_type(4))) float floatx4;      // 16x16 MFMA C/D frag
typedef __attribute__((ext_vector_type(16))) float floatx16;    // 32x32 MFMA C/D frag
typedef __attribute__((ext_vector_type(8))) unsigned short ush8;

__device__ __forceinline__ unsigned short f2bf(float f) {
  union { float f; unsigned int u; } v; v.f = f;
  unsigned int r = v.u + 0x7fffu + ((v.u >> 16) & 1u);  // RNE
  return (unsigned short)(r >> 16);
}
__device__ __forceinline__ float bf2f(unsigned short u) {
  union { unsigned int u; float f; } v; v.u = ((unsigned int)u) << 16;
  return v.f;
}
__device__ __forceinline__ unsigned int pk2(float a, float b) {  // {lo=bf16(a), hi=bf16(b)}
  unsigned int r;
  asm("v_cvt_pk_bf16_f32 %0, %1, %2" : "=v"(r) : "v"(a), "v"(b));
  return r;
}
__device__ __forceinline__ void glds16(const void* g, void* l) {
  __builtin_amdgcn_global_load_lds(
      (__attribute__((address_space(1))) void*)g,
      (__attribute__((address_space(3))) void*)l, 16, 0, 0);
}

// -------- weights: transposed bf16 Wqkv^T [1536][512], Wo^T [512][512], bias_qkv --------
__global__ __launch_bounds__(256) void k_conv_w(
    const float* __restrict__ Wq, const float* __restrict__ Wk,
    const float* __restrict__ Wv, const float* __restrict__ Wo,
    const float* __restrict__ bq, const float* __restrict__ bk, const float* __restrict__ bv,
    unsigned short* __restrict__ Wqkvt, unsigned short* __restrict__ Wot,
    float* __restrict__ biasqkv) {
  int idx = blockIdx.x * 256 + threadIdx.x;
  {
    int nn = idx >> 9, k = idx & 511;
    const float* W = (nn < 512) ? Wq : ((nn < 1024) ? Wk : Wv);
    int n = nn & 511;
    Wqkvt[idx] = f2bf(W[k * 512 + n]);
  }
  if (idx < 512 * 512) {
    int n = idx >> 9, k = idx & 511;
    Wot[idx] = f2bf(Wo[k * 512 + n]);
  }
  if (idx < 1536) {
    biasqkv[idx] = (idx < 512) ? bq[idx] : ((idx < 1024) ? bk[idx - 512] : bv[idx - 1024]);
  }
}

// ---------------- external token QKV fp32: EQKV[16][1536] (q pre-scaled) ----------------
__global__ __launch_bounds__(256) void k_ext_qkv(
    const float* __restrict__ ext,
    const float* __restrict__ Wq, const float* __restrict__ Wk, const float* __restrict__ Wv,
    const float* __restrict__ bq, const float* __restrict__ bk, const float* __restrict__ bv,
    float* __restrict__ EQKV) {
  int b = blockIdx.x / 6, c = blockIdx.x % 6;
  int nn = c * 256 + threadIdx.x;
  __shared__ float xs[512];
  xs[threadIdx.x] = ext[b * 512 + threadIdx.x];
  xs[256 + threadIdx.x] = ext[b * 512 + 256 + threadIdx.x];
  __syncthreads();
  const float* W; const float* bias; float scale = 1.f; int n;
  if (nn < 512)      { W = Wq; bias = bq; n = nn;        scale = ATT_SCALE; }
  else if (nn < 1024){ W = Wk; bias = bk; n = nn - 512; }
  else               { W = Wv; bias = bv; n = nn - 1024; }
  float acc = 0.f;
  #pragma unroll 8
  for (int k = 0; k < 512; ++k) acc += xs[k] * W[k * 512 + n];
  EQKV[b * 1536 + nn] = (acc + bias[n]) * scale;
}

// ======= QKV GEMM fused with x fp32->bf16: C[32768][1536] = cvt(X)[32768][512] * Wqkv^T =======
// 128x128 tile, 4 waves (2Mx2N), BK=64, DOUBLE-buffered 64 KB LDS, 1 raw barrier/K-tile.
// A: reg-staged from fp32 (8 float4 loads -> cvt_pk -> 4 ds_write_b128, swizzled slots).
// B: global_load_lds with pre-swizzled source. LDS rows 128 B, slot s ^= (row&7): conflict-free.
__global__ __launch_bounds__(256, 2) void k_gemm_qkv(
    const float* __restrict__ X, const unsigned short* __restrict__ B,
    const float* __restrict__ bias, unsigned short* __restrict__ C) {
  __shared__ __align__(16) unsigned short S[32768];  // bufA0 bufA1 bufB0 bufB1 x 16 KB
  int tid = threadIdx.x, lane = tid & 63, wv = tid >> 6;
  int lo = lane & 15, hi = lane >> 4;
  int waveM = wv >> 1, waveN = wv & 1;

  int nwg = gridDim.x;  // 3072, %8==0
  int wg = (blockIdx.x & 7) * (nwg >> 3) + (blockIdx.x >> 3);
  int bm = wg / 12, bn = wg % 12;

  const float* Xb = X + (size_t)bm * 128 * 512;
  const unsigned short* Bb = B + (size_t)bn * 128 * 512;
  int arow = tid >> 1, ahalf = tid & 1;
  const float* xrow = Xb + (size_t)arow * 512 + ahalf * 32;

  float4 fA[8];
  auto loadA = [&](int kt) {
    #pragma unroll
    for (int i = 0; i < 8; ++i) fA[i] = *(const float4*)(xrow + kt * 64 + i * 4);
  };
  auto stageB = [&](int kt, int c) {
    unsigned short* lB = S + 16384 + c * 8192;
    #pragma unroll
    for (int i = 0; i < 4; ++i) {
      int chunk = i * 256 + tid, row = chunk >> 3, slot = chunk & 7;
      glds16(Bb + (size_t)row * 512 + kt * 64 + ((slot ^ (row & 7)) << 3),
             lB + (size_t)(i * 256 + wv * 64) * 8);
    }
  };
  auto writeA = [&](int c) {
    unsigned short* lA = S + c * 8192;
    #pragma unroll
    for (int j = 0; j < 4; ++j) {
      uint4 w;
      w.x = pk2(fA[2 * j].x, fA[2 * j].y);
      w.y = pk2(fA[2 * j].z, fA[2 * j].w);
      w.z = pk2(fA[2 * j + 1].x, fA[2 * j + 1].y);
      w.w = pk2(fA[2 * j + 1].z, fA[2 * j + 1].w);
      *(uint4*)((char*)lA + arow * 128 + (((ahalf * 4 + j) ^ (arow & 7)) << 4)) = w;
    }
  };

  floatx4 acc[4][4];
  #pragma unroll
  for (int m = 0; m < 4; ++m)
    #pragma unroll
    for (int n = 0; n < 4; ++n) acc[m][n] = floatx4{0.f, 0.f, 0.f, 0.f};

  loadA(0);
  stageB(0, 0);
  asm volatile("s_waitcnt vmcnt(0)" ::: "memory");
  writeA(0);
  asm volatile("s_waitcnt lgkmcnt(0)" ::: "memory");
  __builtin_amdgcn_sched_barrier(0);
  __builtin_amdgcn_s_barrier();

  for (int t = 0; t < 8; ++t) {
    const unsigned short* lA = S + (t & 1) * 8192;
    const unsigned short* lB = S + 16384 + (t & 1) * 8192;
    if (t < 7) { loadA(t + 1); stageB(t + 1, (t + 1) & 1); }  // overlap with compute below

    bhalf8 af[4][2], bf4[4][2];
    #pragma unroll
    for (int m = 0; m < 4; ++m) {
      int row = waveM * 64 + m * 16 + lo;
      #pragma unroll
      for (int ks = 0; ks < 2; ++ks)
        af[m][ks] = *(const bhalf8*)(lA + (size_t)row * 64 + (((ks * 4 + hi) ^ (row & 7)) << 3));
    }
    #pragma unroll
    for (int n = 0; n < 4; ++n) {
      int row = waveN * 64 + n * 16 + lo;
      #pragma unroll
      for (int ks = 0; ks < 2; ++ks)
        bf4[n][ks] = *(const bhalf8*)(lB + (size_t)row * 64 + (((ks * 4 + hi) ^ (row & 7)) << 3));
    }
    #pragma unroll
    for (int m = 0; m < 4; ++m)
      #pragma unroll
      for (int n = 0; n < 4; ++n) {
        acc[m][n] = __builtin_amdgcn_mfma_f32_16x16x32_bf16(af[m][0], bf4[n][0], acc[m][n], 0, 0, 0);
        acc[m][n] = __builtin_amdgcn_mfma_f32_16x16x32_bf16(af[m][1], bf4[n][1], acc[m][n], 0, 0, 0);
      }

    if (t < 7) {
      __builtin_amdgcn_sched_barrier(0);                 // keep MFMAs above the drain
      asm volatile("s_waitcnt vmcnt(0)" ::: "memory");   // fA(t+1) regs + B(t+1) glds landed
      writeA((t + 1) & 1);
      asm volatile("s_waitcnt lgkmcnt(0)" ::: "memory"); // A ds_writes visible
      __builtin_amdgcn_sched_barrier(0);
      __builtin_amdgcn_s_barrier();                      // buf t&1 reads done chip-wide
    }
  }

  #pragma unroll
  for (int m = 0; m < 4; ++m) {
    int row0 = bm * 128 + waveM * 64 + m * 16 + hi * 4;
    #pragma unroll
    for (int n = 0; n < 4; ++n) {
      int col = bn * 128 + waveN * 64 + n * 16 + lo;
      float bb = bias[col];
      #pragma unroll
      for (int r = 0; r < 4; ++r) {
        float v = acc[m][n][r] + bb;
        if (col < 512) v *= ATT_SCALE;
        C[(size_t)(row0 + r) * 1536 + col] = f2bf(v);
      }
    }
  }
}

// ======= output GEMM: C[32768][512] f32 = mainb[32768][512]bf16 * Wo^T + bo =======
// Same 128x128 dbuf structure, both operands via global_load_lds.
__global__ __launch_bounds__(256, 2) void k_gemm_out(
    const unsigned short* __restrict__ A, const unsigned short* __restrict__ B,
    const float* __restrict__ bias, float* __restrict__ C) {
  __shared__ __align__(16) unsigned short S[32768];
  int tid = threadIdx.x, lane = tid & 63, wv = tid >> 6;
  int lo = lane & 15, hi = lane >> 4;
  int waveM = wv >> 1, waveN = wv & 1;

  int nwg = gridDim.x;  // 1024
  int wg = (blockIdx.x & 7) * (nwg >> 3) + (blockIdx.x >> 3);
  int bm = wg / 4, bn = wg % 4;

  const unsigned short* Ab = A + (size_t)bm * 128 * 512;
  const unsigned short* Bb = B + (size_t)bn * 128 * 512;

  auto stage = [&](int kt, int c) {
    unsigned short* lA = S + c * 8192;
    unsigned short* lB = S + 16384 + c * 8192;
    #pragma unroll
    for (int i = 0; i < 4; ++i) {
      int chunk = i * 256 + tid, row = chunk >> 3, slot = chunk & 7;
      glds16(Ab + (size_t)row * 512 + kt * 64 + ((slot ^ (row & 7)) << 3),
             lA + (size_t)(i * 256 + wv * 64) * 8);
    }
    #pragma unroll
    for (int i = 0; i < 4; ++i) {
      int chunk = i * 256 + tid, row = chunk >> 3, slot = chunk & 7;
      glds16(Bb + (size_t)row * 512 + kt * 64 + ((slot ^ (row & 7)) << 3),
             lB + (size_t)(i * 256 + wv * 64) * 8);
    }
  };

  floatx4 acc[4][4];
  #pragma unroll
  for (int m = 0; m < 4; ++m)
    #pragma unroll
    for (int n = 0; n < 4; ++n) acc[m][n] = floatx4{0.f, 0.f, 0.f, 0.f};

  stage(0, 0);
  asm volatile("s_waitcnt vmcnt(0)" ::: "memory");
  __builtin_amdgcn_s_barrier();

  for (int t = 0; t < 8; ++t) {
    const unsigned short* lA = S + (t & 1) * 8192;
    const unsigned short* lB = S + 16384 + (t & 1) * 8192;
    if (t < 7) stage(t + 1, (t + 1) & 1);

    bhalf8 af[4][2], bf4[4][2];
    #pragma unroll
    for (int m = 0; m < 4; ++m) {
      int row = waveM * 64 + m * 16 + lo;
      #pragma unroll
      for (int ks = 0; ks < 2; ++ks)
        af[m][ks] = *(const bhalf8*)(lA + (size_t)row * 64 + (((ks * 4 + hi) ^ (row & 7)) << 3));
    }
    #pragma unroll
    for (int n = 0; n < 4; ++n) {
      int row = waveN * 64 + n * 16 + lo;
      #pragma unroll
      for (int ks = 0; ks < 2; ++ks)
        bf4[n][ks] = *(const bhalf8*)(lB + (size_t)row * 64 + (((ks * 4 + hi) ^ (row & 7)) << 3));
    }
    #pragma unroll
    for (int m = 0; m < 4; ++m)
      #pragma unroll
      for (int n = 0; n < 4; ++n) {
        acc[m][n] = __builtin_amdgcn_mfma_f32_16x16x32_bf16(af[m][0], bf4[n][0], acc[m][n], 0, 0, 0);
        acc[m][n] = __builtin_amdgcn_mfma_f32_16x16x32_bf16(af[m][1], bf4[n][1], acc[m][n], 0, 0, 0);
      }

    if (t < 7) {
      __builtin_amdgcn_sched_barrier(0);
      asm volatile("s_waitcnt vmcnt(0)" ::: "memory");
      __builtin_amdgcn_sched_barrier(0);
      __builtin_amdgcn_s_barrier();
    }
  }

  #pragma unroll
  for (int m = 0; m < 4; ++m) {
    int row0 = bm * 128 + waveM * 64 + m * 16 + hi * 4;
    #pragma unroll
    for (int n = 0; n < 4; ++n) {
      int col = bn * 128 + waveN * 64 + n * 16 + lo;
      float bb = bias[col];
      #pragma unroll
      for (int r = 0; r < 4; ++r)
        C[(size_t)(row0 + r) * 512 + col] = acc[m][n][r] + bb;
    }
  }
}

// ---------------- fused attention v2: 32x32 swapped-QK^T, in-register softmax ----------------
// grid = 1024 groups (b,h,j); 8 warps x 32 queries; keys 0..256 (+pad to 288, masked).
#define VTC 296  // Vt row stride elems: 592B rows -> b128 read starts tile all 32 banks
__global__ __launch_bounds__(512, 4) void k_attn(
    const unsigned short* __restrict__ QKV,   // [32768][1536] bf16 (q scaled)
    const float* __restrict__ EQKV,           // [16][1536] f32
    unsigned short* __restrict__ mainb) {     // [32768][512] bf16
  __shared__ __align__(16) unsigned short Ks[288 * 64];  // rows XOR-swizzled; reused as epilogue buf
  __shared__ __align__(16) unsigned short Vt[64 * VTC];  // [d][key] transposed
  int g = blockIdx.x;
  int b = g >> 6, h = (g >> 3) & 7, j = g & 7;
  int tid = threadIdx.x, lane = tid & 63, wv = tid >> 6;
  int ql = lane & 31, hb = lane >> 5;
  const size_t rowbase = (size_t)b * 2048 + (size_t)j * 256;
  const unsigned short* Kg = QKV + rowbase * 1536 + 512 + h * 64;
  const unsigned short* Vg = QKV + rowbase * 1536 + 1024 + h * 64;

  // Q fragments early (HBM latency overlaps staging). B-frag: col=q=ql, k=hb*8+u.
  int qbase = wv * 32;
  const unsigned short* qp = QKV + (rowbase + qbase + ql) * 1536 + h * 64 + hb * 8;
  bhalf8 qf[4];
  #pragma unroll
  for (int c = 0; c < 4; ++c) qf[c] = *(const bhalf8*)(qp + c * 16);

  // zero Vt (pad keys must be exactly 0; Ks pads are masked in-register)
  {
    ush8 z8 = {0, 0, 0, 0, 0, 0, 0, 0};
    for (int c = tid; c < (64 * VTC) / 8; c += 512) ((ush8*)Vt)[c] = z8;
  }
  __syncthreads();

  // stage K rows 1..256 via global_load_lds, pre-swizzled source (linear dest)
  {
    int keybase = 1 + wv * 32;
    #pragma unroll
    for (int i = 0; i < 4; ++i) {
      int key = keybase + i * 8 + (lane >> 3);
      int slot = lane & 7;
      const unsigned short* src =
          Kg + (size_t)(key - 1) * 1536 + (((slot * 16) ^ ((key & 7) << 4)) >> 1);
      glds16(src, &Ks[(size_t)(keybase + i * 8) * 64]);
    }
  }
  // stage V transposed: lanes of one instr cover 64 different KEYS -> 2-way banks (free)
  for (int c = tid; c < 2048; c += 512) {
    int key = 1 + (c & 255), d0 = (c >> 8) * 8;
    ush8 vv = *(const ush8*)(Vg + (size_t)(key - 1) * 1536 + d0);
    #pragma unroll
    for (int u = 0; u < 8; ++u) Vt[(d0 + u) * VTC + key] = vv[u];
  }
  // key 0 (external token), fp32 source
  if (wv == 0) {
    Ks[lane] = f2bf(EQKV[b * 1536 + 512 + h * 64 + lane]);       // row 0 unswizzled (0&7==0)
    Vt[lane * VTC] = f2bf(EQKV[b * 1536 + 1024 + h * 64 + lane]);
  }
  __syncthreads();  // drains vmcnt (glds) + lgkmcnt

  floatx16 o0, o1;
  #pragma unroll
  for (int i = 0; i < 16; ++i) { o0[i] = 0.f; o1[i] = 0.f; }
  float m = -1e30f, lsum = 0.f;

  #pragma unroll
  for (int t = 0; t < 9; ++t) {
    // S^T tile (32 keys x 32 q): A=K[key][d], B=Q[q][d]
    floatx16 s;
    #pragma unroll
    for (int i = 0; i < 16; ++i) s[i] = 0.f;
    int key = t * 32 + ql;
    #pragma unroll
    for (int c = 0; c < 4; ++c) {
      bhalf8 kf = *(const bhalf8*)((const char*)Ks + key * 128 +
                                   ((c * 32 + hb * 16) ^ ((key & 7) << 4)));
      s = __builtin_amdgcn_mfma_f32_32x32x16_bf16(kf, qf[c], s, 0, 0, 0);
    }
    if (t == 8) {  // keys 257..287 are pad: real only local key 0 = (hb==0, r==0)
      #pragma unroll
      for (int r = 0; r < 16; ++r) {
        if (r == 0) { if (hb != 0) s[0] = -1e30f; }
        else s[r] = -1e30f;
      }
    }
    // online softmax: lane holds 16 of this tile's 32 keys for q=ql; partner holds rest
    float mt = s[0];
    #pragma unroll
    for (int r = 1; r < 16; ++r) mt = fmaxf(mt, s[r]);
    mt = fmaxf(mt, __shfl_xor(mt, 32, 64));
    if (!__all(mt - m <= 8.f)) {   // defer-max (T13)
      float mnew = fmaxf(m, mt);
      float corr = __expf(m - mnew);
      lsum *= corr;
      #pragma unroll
      for (int r = 0; r < 16; ++r) { o0[r] *= corr; o1[r] *= corr; }
      m = mnew;
    }
    float p[16]; float ts = 0.f;
    #pragma unroll
    for (int r = 0; r < 16; ++r) { p[r] = __expf(s[r] - m); ts += p[r]; }
    lsum += ts;
    // pack P to bf16 pairs; exchange across lane halves to build PV B-frags
    unsigned int pk[8], qk[8];
    #pragma unroll
    for (int i = 0; i < 8; ++i)
      pk[i] = (unsigned int)f2bf(p[2 * i]) | ((unsigned int)f2bf(p[2 * i + 1]) << 16);
    #pragma unroll
    for (int i = 0; i < 8; ++i) qk[i] = __shfl_xor(pk[i], 32, 64);
    bhalf8 f0, f1;
    unsigned int* f0u = (unsigned int*)&f0;
    unsigned int* f1u = (unsigned int*)&f1;
    if (hb == 0) {
      f0u[0] = pk[0]; f0u[1] = pk[1]; f0u[2] = qk[0]; f0u[3] = qk[1];
      f1u[0] = pk[4]; f1u[1] = pk[5]; f1u[2] = qk[4]; f1u[3] = qk[5];
    } else {
      f0u[0] = qk[2]; f0u[1] = qk[3]; f0u[2] = pk[2]; f0u[3] = pk[3];
      f1u[0] = qk[6]; f1u[1] = qk[7]; f1u[2] = pk[6]; f1u[3] = pk[7];
    }
    // O^T += V^T * P^T : A=Vt[d][key] (contiguous b128), B=P frags
    {
      const char* vb0 = (const char*)Vt + ((0 * 32 + ql) * VTC + t * 32 + hb * 8) * 2;
      bhalf8 v0 = *(const bhalf8*)vb0;
      bhalf8 v1 = *(const bhalf8*)(vb0 + 32);
      o0 = __builtin_amdgcn_mfma_f32_32x32x16_bf16(v0, f0, o0, 0, 0, 0);
      o0 = __builtin_amdgcn_mfma_f32_32x32x16_bf16(v1, f1, o0, 0, 0, 0);
      const char* vb1 = (const char*)Vt + ((1 * 32 + ql) * VTC + t * 32 + hb * 8) * 2;
      bhalf8 w0 = *(const bhalf8*)vb1;
      bhalf8 w1 = *(const bhalf8*)(vb1 + 32);
      o1 = __builtin_amdgcn_mfma_f32_32x32x16_bf16(w0, f0, o1, 0, 0, 0);
      o1 = __builtin_amdgcn_mfma_f32_32x32x16_bf16(w1, f1, o1, 0, 0, 0);
    }
  }

  lsum += __shfl_xor(lsum, 32, 64);
  float rinv = 1.f / lsum;
  __syncthreads();  // all K reads done; reuse Ks as per-warp transpose buffer
  char* ob = (char*)(Ks + wv * 2048);  // 32q x 64d bf16 = 4KB per warp
  #pragma unroll
  for (int dt = 0; dt < 2; ++dt) {
    #pragma unroll
    for (int i = 0; i < 8; ++i) {
      int d0 = dt * 32 + ((2 * i) & 3) + 8 * (i >> 1) + 4 * hb;  // pair (d0, d0+1)
      float a = (dt ? o1[2 * i] : o0[2 * i]) * rinv;
      float c = (dt ? o1[2 * i + 1] : o0[2 * i + 1]) * rinv;
      unsigned int w = (unsigned int)f2bf(a) | ((unsigned int)f2bf(c) << 16);
      *(unsigned int*)(ob + ql * 128 + ((d0 * 2) ^ ((ql & 7) << 4))) = w;
    }
  }
  #pragma unroll
  for (int i = 0; i < 4; ++i) {
    int chunk = i * 64 + lane;  // 256 chunks = 32 q x 8 slots
    int q = chunk >> 3, slot = chunk & 7;
    bhalf8 vv = *(const bhalf8*)(ob + q * 128 + ((slot * 16) ^ ((q & 7) << 4)));
    *(bhalf8*)(mainb + (rowbase + qbase + q) * 512 + h * 64 + slot * 8) = vv;
  }
}

// ---------------- external query attention (j==1 keys), 256 threads ----------------
__global__ __launch_bounds__(256) void k_ext_attn(
    const unsigned short* __restrict__ QKV, const float* __restrict__ EQKV,
    float* __restrict__ extpre) {
  int b = blockIdx.x >> 3, h = blockIdx.x & 7;
  int tid = threadIdx.x, lane = tid & 63, wv = tid >> 6;
  __shared__ float qs[64];
  __shared__ float ps[257];
  __shared__ float red[8];
  __shared__ float acc4[4][64];
  if (tid < 64) qs[tid] = EQKV[b * 1536 + h * 64 + tid];
  __syncthreads();
  const size_t base = (size_t)b * 2048 + 256;  // rows of chunk j=1
  float sc[2] = {-1e30f, -1e30f};
  #pragma unroll
  for (int it = 0; it < 2; ++it) {
    int key = tid + it * 256;
    if (key < 257) {
      float s = 0.f;
      if (key == 0) {
        const float* kr = EQKV + b * 1536 + 512 + h * 64;
        #pragma unroll 8
        for (int d = 0; d < 64; ++d) s += qs[d] * kr[d];
      } else {
        const unsigned short* kr = QKV + (base + key - 1) * 1536 + 512 + h * 64;
        #pragma unroll
        for (int c = 0; c < 8; ++c) {
          ush8 kv = *(const ush8*)(kr + c * 8);
          #pragma unroll
          for (int u = 0; u < 8; ++u) s += qs[c * 8 + u] * bf2f(kv[u]);
        }
      }
      sc[it] = s;
    }
  }
  float lmax = fmaxf(sc[0], sc[1]);
  for (int d = 1; d < 64; d <<= 1) lmax = fmaxf(lmax, __shfl_xor(lmax, d, 64));
  if (lane == 0) red[wv] = lmax;
  __syncthreads();
  float M = fmaxf(fmaxf(red[0], red[1]), fmaxf(red[2], red[3]));
  float lsum = 0.f;
  #pragma unroll
  for (int it = 0; it < 2; ++it) {
    int key = tid + it * 256;
    if (key < 257) { float p = __expf(sc[it] - M); ps[key] = p; lsum += p; }
  }
  for (int d = 1; d < 64; d <<= 1) lsum += __shfl_xor(lsum, d, 64);
  if (lane == 0) red[4 + wv] = lsum;
  __syncthreads();
  float S = red[4] + red[5] + red[6] + red[7];
  int d = tid & 63, part = tid >> 6;
  float acc = 0.f;
  for (int key = part; key < 257; key += 4) {
    float vv = (key == 0) ? EQKV[b * 1536 + 1024 + h * 64 + d]
                          : bf2f(QKV[(base + key - 1) * 1536 + 1024 + h * 64 + d]);
    acc += ps[key] * vv;
  }
  acc4[part][d] = acc;
  __syncthreads();
  if (tid < 64) {
    float r = (acc4[0][tid] + acc4[1][tid] + acc4[2][tid] + acc4[3][tid]) / S;
    extpre[b * 512 + h * 64 + tid] = r;
  }
}

// ---------------- external output projection: ext_pre[16][512] @ Wo + bo (fp32) ----------------
__global__ __launch_bounds__(256) void k_ext_out(
    const float* __restrict__ extpre, const float* __restrict__ Wo,
    const float* __restrict__ bo, float* __restrict__ out) {
  int b = blockIdx.x, half = blockIdx.y;
  int n = half * 256 + threadIdx.x;
  __shared__ float xs[512];
  xs[threadIdx.x] = extpre[b * 512 + threadIdx.x];
  xs[256 + threadIdx.x] = extpre[b * 512 + 256 + threadIdx.x];
  __syncthreads();
  float acc = bo[n];
  #pragma unroll 8
  for (int k = 0; k < 512; ++k) acc += xs[k] * Wo[k * 512 + n];
  out[16777216 + b * 512 + n] = acc;
}

extern "C" void kernel_launch(void* const* d_in, const int* in_sizes, int n_in,
                              void* d_out, int out_size, void* d_ws, size_t ws_size,
                              hipStream_t stream) {
  (void)in_sizes; (void)n_in; (void)out_size; (void)ws_size;
  const float* x   = (const float*)d_in[0];
  const float* ext = (const float*)d_in[1];
  const float* Wq  = (const float*)d_in[2];
  const float* bq  = (const float*)d_in[3];
  const float* Wk  = (const float*)d_in[4];
  const float* bk  = (const float*)d_in[5];
  const float* Wv  = (const float*)d_in[6];
  const float* bv  = (const float*)d_in[7];
  const float* Wo  = (const float*)d_in[8];
  const float* bo  = (const float*)d_in[9];
  float* out = (float*)d_out;

  char* ws = (char*)d_ws;
  size_t off = 0;
  auto take = [&](size_t bytes) { char* p = ws + off; off += (bytes + 255) & ~(size_t)255; return p; };
  unsigned short* Wqkvt  = (unsigned short*)take((size_t)1536 * 512 * 2);
  unsigned short* Wot    = (unsigned short*)take((size_t)512 * 512 * 2);
  float*          biasqkv= (float*)take(1536 * 4);
  float*          EQKV   = (float*)take(16 * 1536 * 4);
  unsigned short* QKVb   = (unsigned short*)take((size_t)32768 * 1536 * 2);
  unsigned short* mainb  = (unsigned short*)take((size_t)32768 * 512 * 2);
  float*          extpre = (float*)take(16 * 512 * 4);

  k_conv_w<<<3072, 256, 0, stream>>>(Wq, Wk, Wv, Wo, bq, bk, bv, Wqkvt, Wot, biasqkv);
  k_ext_qkv<<<96, 256, 0, stream>>>(ext, Wq, Wk, Wv, bq, bk, bv, EQKV);
  k_gemm_qkv<<<3072, 256, 0, stream>>>(x, Wqkvt, biasqkv, QKVb);   // 256 bm x 12 bn
  k_attn<<<1024, 512, 0, stream>>>(QKVb, EQKV, mainb);
  k_ext_attn<<<128, 256, 0, stream>>>(QKVb, EQKV, extpre);
  k_gemm_out<<<1024, 256, 0, stream>>>(mainb, Wot, bo, out);       // 256 bm x 4 bn
  k_ext_out<<<dim3(16, 2), 256, 0, stream>>>(extpre, Wo, bo, out);
}

// Round 9
// 220.697 us; speedup vs baseline: 1.2710x; 1.2710x over previous
//
#include <hip/hip_runtime.h>
#include <stdint.h>

// Problem constants: b=16, f=8, n=256, N=2048, dim=512, H=8, DH=64, keys/group=257
#define ATT_SCALE 0.125f

typedef __attribute__((ext_vector_type(8))) short bhalf8;       // 8 bf16 = 4 VGPR (MFMA A/B frag)
typedef __attribute__((ext_vector_type(4))) float floatx4;      // 16x16 MFMA C/D frag
typedef __attribute__((ext_vector_type(16))) float floatx16;    // 32x32 MFMA C/D frag
typedef __attribute__((ext_vector_type(8))) unsigned short ush8;

__device__ __forceinline__ unsigned short f2bf(float f) {
  union { float f; unsigned int u; } v; v.f = f;
  unsigned int r = v.u + 0x7fffu + ((v.u >> 16) & 1u);  // RNE
  return (unsigned short)(r >> 16);
}
__device__ __forceinline__ float bf2f(unsigned short u) {
  union { unsigned int u; float f; } v; v.u = ((unsigned int)u) << 16;
  return v.f;
}
// {lo=bf16(a), hi=bf16(b)} RNE — verified safe in round 6 (fused staging path, absmax 4.88e-4)
__device__ __forceinline__ unsigned int pk2(float a, float b) {
  unsigned int r;
  asm("v_cvt_pk_bf16_f32 %0, %1, %2" : "=v"(r) : "v"(a), "v"(b));
  return r;
}
__device__ __forceinline__ void glds16(const void* g, void* l) {
  __builtin_amdgcn_global_load_lds(
      (__attribute__((address_space(1))) void*)g,
      (__attribute__((address_space(3))) void*)l, 16, 0, 0);
}

// ---------------- fp32 -> bf16 conversion of x (16.78M elems) ----------------
__global__ __launch_bounds__(256) void k_conv_x(const float* __restrict__ x,
                                                unsigned short* __restrict__ out) {
  int i = blockIdx.x * 256 + threadIdx.x;
  float4 v = ((const float4*)x)[i];
  ((uint2*)out)[i] = make_uint2(pk2(v.x, v.y), pk2(v.z, v.w));
}

// -------- weights: transposed bf16 Wqkv^T [1536][512], Wo^T [512][512], bias_qkv --------
__global__ __launch_bounds__(256) void k_conv_w(
    const float* __restrict__ Wq, const float* __restrict__ Wk,
    const float* __restrict__ Wv, const float* __restrict__ Wo,
    const float* __restrict__ bq, const float* __restrict__ bk, const float* __restrict__ bv,
    unsigned short* __restrict__ Wqkvt, unsigned short* __restrict__ Wot,
    float* __restrict__ biasqkv) {
  int idx = blockIdx.x * 256 + threadIdx.x;
  {
    int nn = idx >> 9, k = idx & 511;
    const float* W = (nn < 512) ? Wq : ((nn < 1024) ? Wk : Wv);
    int n = nn & 511;
    Wqkvt[idx] = f2bf(W[k * 512 + n]);
  }
  if (idx < 512 * 512) {
    int n = idx >> 9, k = idx & 511;
    Wot[idx] = f2bf(Wo[k * 512 + n]);
  }
  if (idx < 1536) {
    biasqkv[idx] = (idx < 512) ? bq[idx] : ((idx < 1024) ? bk[idx - 512] : bv[idx - 1024]);
  }
}

// ---------------- external token QKV fp32: EQKV[16][1536] (q pre-scaled) ----------------
__global__ __launch_bounds__(256) void k_ext_qkv(
    const float* __restrict__ ext,
    const float* __restrict__ Wq, const float* __restrict__ Wk, const float* __restrict__ Wv,
    const float* __restrict__ bq, const float* __restrict__ bk, const float* __restrict__ bv,
    float* __restrict__ EQKV) {
  int b = blockIdx.x / 6, c = blockIdx.x % 6;
  int nn = c * 256 + threadIdx.x;
  __shared__ float xs[512];
  xs[threadIdx.x] = ext[b * 512 + threadIdx.x];
  xs[256 + threadIdx.x] = ext[b * 512 + 256 + threadIdx.x];
  __syncthreads();
  const float* W; const float* bias; float scale = 1.f; int n;
  if (nn < 512)      { W = Wq; bias = bq; n = nn;        scale = ATT_SCALE; }
  else if (nn < 1024){ W = Wk; bias = bk; n = nn - 512; }
  else               { W = Wv; bias = bv; n = nn - 1024; }
  float acc = 0.f;
  #pragma unroll 8
  for (int k = 0; k < 512; ++k) acc += xs[k] * W[k * 512 + n];
  EQKV[b * 1536 + nn] = (acc + bias[n]) * scale;
}

// =============== 128x128-tile MFMA GEMM, m97 2-barrier loop, BK=64, XOR-swizzled LDS ===============
// (round-5 proven: 60.4 us, MfmaUtil 37%, SQ_LDS_BANK_CONFLICT 0) — unchanged
template <int EPI>
__global__ __launch_bounds__(256, 2) void k_gemm(
    const unsigned short* __restrict__ A, const unsigned short* __restrict__ B,
    const float* __restrict__ bias, void* __restrict__ Cptr, int N, int nbn) {
  __shared__ __align__(16) unsigned short S[16384];  // A 16 KB + B 16 KB
  int tid = threadIdx.x, lane = tid & 63, wv = tid >> 6;
  int lo = lane & 15, hi = lane >> 4;
  int waveM = wv >> 1, waveN = wv & 1;

  int nwg = gridDim.x;
  int wg = (blockIdx.x & 7) * (nwg >> 3) + (blockIdx.x >> 3);
  int bm = wg / nbn, bn = wg % nbn;

  const unsigned short* Ab = A + (size_t)bm * 128 * 512;
  const unsigned short* Bb = B + (size_t)bn * 128 * 512;
  unsigned short* lA = S;
  unsigned short* lB = S + 8192;

  floatx4 acc[4][4];
  #pragma unroll
  for (int m = 0; m < 4; ++m)
    #pragma unroll
    for (int n = 0; n < 4; ++n) acc[m][n] = floatx4{0.f, 0.f, 0.f, 0.f};

  for (int kt = 0; kt < 8; ++kt) {
    __syncthreads();
    #pragma unroll
    for (int i = 0; i < 4; ++i) {
      int chunk = i * 256 + tid;
      int row = chunk >> 3, slot = chunk & 7;
      glds16(Ab + (size_t)row * 512 + kt * 64 + ((slot ^ (row & 7)) << 3),
             lA + (size_t)(i * 256 + wv * 64) * 8);
    }
    #pragma unroll
    for (int i = 0; i < 4; ++i) {
      int chunk = i * 256 + tid;
      int row = chunk >> 3, slot = chunk & 7;
      glds16(Bb + (size_t)row * 512 + kt * 64 + ((slot ^ (row & 7)) << 3),
             lB + (size_t)(i * 256 + wv * 64) * 8);
    }
    __syncthreads();

    bhalf8 af[4][2], bf4[4][2];
    #pragma unroll
    for (int m = 0; m < 4; ++m) {
      int row = waveM * 64 + m * 16 + lo;
      #pragma unroll
      for (int ks = 0; ks < 2; ++ks)
        af[m][ks] = *(const bhalf8*)(lA + (size_t)row * 64 + (((ks * 4 + hi) ^ (row & 7)) << 3));
    }
    #pragma unroll
    for (int n = 0; n < 4; ++n) {
      int row = waveN * 64 + n * 16 + lo;
      #pragma unroll
      for (int ks = 0; ks < 2; ++ks)
        bf4[n][ks] = *(const bhalf8*)(lB + (size_t)row * 64 + (((ks * 4 + hi) ^ (row & 7)) << 3));
    }
    #pragma unroll
    for (int m = 0; m < 4; ++m)
      #pragma unroll
      for (int n = 0; n < 4; ++n) {
        acc[m][n] = __builtin_amdgcn_mfma_f32_16x16x32_bf16(af[m][0], bf4[n][0], acc[m][n], 0, 0, 0);
        acc[m][n] = __builtin_amdgcn_mfma_f32_16x16x32_bf16(af[m][1], bf4[n][1], acc[m][n], 0, 0, 0);
      }
  }

  #pragma unroll
  for (int m = 0; m < 4; ++m) {
    int row0 = bm * 128 + waveM * 64 + m * 16 + hi * 4;
    #pragma unroll
    for (int n = 0; n < 4; ++n) {
      int col = bn * 128 + waveN * 64 + n * 16 + lo;
      float bb = bias[col];
      #pragma unroll
      for (int r = 0; r < 4; ++r) {
        float v = acc[m][n][r] + bb;
        if constexpr (EPI == 0) {
          if (col < 512) v *= ATT_SCALE;
          ((unsigned short*)Cptr)[(size_t)(row0 + r) * N + col] = f2bf(v);
        } else {
          ((float*)Cptr)[(size_t)(row0 + r) * N + col] = v;
        }
      }
    }
  }
}

// ---------------- fused attention v3-safe: 32x32 swapped-QK^T, cvt_pk pack, shfl_xor exchange ----------------
// grid = 1024 groups (b,h,j); 8 warps x 32 queries; keys 0..256 (+pad to 288, masked).
#define VTC 296  // Vt row stride elems
__global__ __launch_bounds__(512, 4) void k_attn(
    const unsigned short* __restrict__ QKV,   // [32768][1536] bf16 (q scaled)
    const float* __restrict__ EQKV,           // [16][1536] f32
    unsigned short* __restrict__ mainb) {     // [32768][512] bf16
  __shared__ __align__(16) unsigned short Ks[288 * 64];  // rows XOR-swizzled; reused as epilogue buf
  __shared__ __align__(16) unsigned short Vt[64 * VTC];  // [d][key] transposed
  int g = blockIdx.x;
  int b = g >> 6, h = (g >> 3) & 7, j = g & 7;
  int tid = threadIdx.x, lane = tid & 63, wv = tid >> 6;
  int ql = lane & 31, hb = lane >> 5;
  const size_t rowbase = (size_t)b * 2048 + (size_t)j * 256;
  const unsigned short* Kg = QKV + rowbase * 1536 + 512 + h * 64;
  const unsigned short* Vg = QKV + rowbase * 1536 + 1024 + h * 64;

  int qbase = wv * 32;
  const unsigned short* qp = QKV + (rowbase + qbase + ql) * 1536 + h * 64 + hb * 8;
  bhalf8 qf[4];
  #pragma unroll
  for (int c = 0; c < 4; ++c) qf[c] = *(const bhalf8*)(qp + c * 16);

  // zero Vt (pad keys must be exactly 0)
  {
    ush8 z8 = {0, 0, 0, 0, 0, 0, 0, 0};
    for (int c = tid; c < (64 * VTC) / 8; c += 512) ((ush8*)Vt)[c] = z8;
  }
  __syncthreads();

  // stage K rows 1..256 via global_load_lds, pre-swizzled source (linear dest)
  {
    int keybase = 1 + wv * 32;
    #pragma unroll
    for (int i = 0; i < 4; ++i) {
      int key = keybase + i * 8 + (lane >> 3);
      int slot = lane & 7;
      const unsigned short* src =
          Kg + (size_t)(key - 1) * 1536 + (((slot * 16) ^ ((key & 7) << 4)) >> 1);
      glds16(src, &Ks[(size_t)(keybase + i * 8) * 64]);
    }
  }
  // stage V transposed: lanes of one instr cover 64 different KEYS -> 2-way banks (free)
  for (int c = tid; c < 2048; c += 512) {
    int key = 1 + (c & 255), d0 = (c >> 8) * 8;
    ush8 vv = *(const ush8*)(Vg + (size_t)(key - 1) * 1536 + d0);
    #pragma unroll
    for (int u = 0; u < 8; ++u) Vt[(d0 + u) * VTC + key] = vv[u];
  }
  // key 0 (external token), fp32 source
  if (wv == 0) {
    Ks[lane] = f2bf(EQKV[b * 1536 + 512 + h * 64 + lane]);       // row 0 unswizzled (0&7==0)
    Vt[lane * VTC] = f2bf(EQKV[b * 1536 + 1024 + h * 64 + lane]);
  }
  __syncthreads();

  floatx16 o0, o1;
  #pragma unroll
  for (int i = 0; i < 16; ++i) { o0[i] = 0.f; o1[i] = 0.f; }
  float m = -1e30f, lsum = 0.f;

  #pragma unroll
  for (int t = 0; t < 9; ++t) {
    // S^T tile (32 keys x 32 q): A=K[key][d], B=Q[q][d]
    floatx16 s;
    #pragma unroll
    for (int i = 0; i < 16; ++i) s[i] = 0.f;
    int key = t * 32 + ql;
    __builtin_amdgcn_s_setprio(1);
    #pragma unroll
    for (int c = 0; c < 4; ++c) {
      bhalf8 kf = *(const bhalf8*)((const char*)Ks + key * 128 +
                                   ((c * 32 + hb * 16) ^ ((key & 7) << 4)));
      s = __builtin_amdgcn_mfma_f32_32x32x16_bf16(kf, qf[c], s, 0, 0, 0);
    }
    __builtin_amdgcn_s_setprio(0);
    if (t == 8) {  // keys 257..287 are pad: real only local key 0 = (hb==0, r==0)
      #pragma unroll
      for (int r = 0; r < 16; ++r) {
        if (r == 0) { if (hb != 0) s[0] = -1e30f; }
        else s[r] = -1e30f;
      }
    }
    // online softmax: lane holds 16 keys for q=ql; partner (lane^32) holds the other 16
    float mt = s[0];
    #pragma unroll
    for (int r = 1; r < 16; ++r) mt = fmaxf(mt, s[r]);
    mt = fmaxf(mt, __shfl_xor(mt, 32, 64));
    if (!__all(mt - m <= 8.f)) {   // defer-max (T13)
      float mnew = fmaxf(m, mt);
      float corr = __expf(m - mnew);
      lsum *= corr;
      #pragma unroll
      for (int r = 0; r < 16; ++r) { o0[r] *= corr; o1[r] *= corr; }
      m = mnew;
    }
    float p[16]; float ts = 0.f;
    #pragma unroll
    for (int r = 0; r < 16; ++r) { p[r] = __expf(s[r] - m); ts += p[r]; }
    lsum += ts;
    // pack P via cvt_pk (verified primitive); exchange via verified __shfl_xor(.,32)
    unsigned int pk[8], qk[8];
    #pragma unroll
    for (int i = 0; i < 8; ++i) pk[i] = pk2(p[2 * i], p[2 * i + 1]);
    #pragma unroll
    for (int i = 0; i < 8; ++i) qk[i] = __shfl_xor(pk[i], 32, 64);
    bhalf8 f0, f1;
    unsigned int* f0u = (unsigned int*)&f0;
    unsigned int* f1u = (unsigned int*)&f1;
    if (hb == 0) {
      f0u[0] = pk[0]; f0u[1] = pk[1]; f0u[2] = qk[0]; f0u[3] = qk[1];
      f1u[0] = pk[4]; f1u[1] = pk[5]; f1u[2] = qk[4]; f1u[3] = qk[5];
    } else {
      f0u[0] = qk[2]; f0u[1] = qk[3]; f0u[2] = pk[2]; f0u[3] = pk[3];
      f1u[0] = qk[6]; f1u[1] = qk[7]; f1u[2] = pk[6]; f1u[3] = pk[7];
    }
    // O^T += V^T * P^T : A=Vt[d][key] (contiguous b128), B=P frags
    {
      const char* vb0 = (const char*)Vt + ((0 * 32 + ql) * VTC + t * 32 + hb * 8) * 2;
      bhalf8 v0 = *(const bhalf8*)vb0;
      bhalf8 v1 = *(const bhalf8*)(vb0 + 32);
      const char* vb1 = (const char*)Vt + ((1 * 32 + ql) * VTC + t * 32 + hb * 8) * 2;
      bhalf8 w0 = *(const bhalf8*)vb1;
      bhalf8 w1 = *(const bhalf8*)(vb1 + 32);
      __builtin_amdgcn_s_setprio(1);
      o0 = __builtin_amdgcn_mfma_f32_32x32x16_bf16(v0, f0, o0, 0, 0, 0);
      o0 = __builtin_amdgcn_mfma_f32_32x32x16_bf16(v1, f1, o0, 0, 0, 0);
      o1 = __builtin_amdgcn_mfma_f32_32x32x16_bf16(w0, f0, o1, 0, 0, 0);
      o1 = __builtin_amdgcn_mfma_f32_32x32x16_bf16(w1, f1, o1, 0, 0, 0);
      __builtin_amdgcn_s_setprio(0);
    }
  }

  lsum += __shfl_xor(lsum, 32, 64);
  float rinv = 1.f / lsum;
  __syncthreads();  // all K reads done; reuse Ks as per-warp transpose buffer
  char* ob = (char*)(Ks + wv * 2048);  // 32q x 64d bf16 = 4KB per warp
  #pragma unroll
  for (int dt = 0; dt < 2; ++dt) {
    #pragma unroll
    for (int i = 0; i < 8; ++i) {
      int d0 = dt * 32 + ((2 * i) & 3) + 8 * (i >> 1) + 4 * hb;  // pair (d0, d0+1)
      float a = (dt ? o1[2 * i] : o0[2 * i]) * rinv;
      float c = (dt ? o1[2 * i + 1] : o0[2 * i + 1]) * rinv;
      *(unsigned int*)(ob + ql * 128 + ((d0 * 2) ^ ((ql & 7) << 4))) = pk2(a, c);
    }
  }
  #pragma unroll
  for (int i = 0; i < 4; ++i) {
    int chunk = i * 64 + lane;  // 256 chunks = 32 q x 8 slots
    int q = chunk >> 3, slot = chunk & 7;
    bhalf8 vv = *(const bhalf8*)(ob + q * 128 + ((slot * 16) ^ ((q & 7) << 4)));
    *(bhalf8*)(mainb + (rowbase + qbase + q) * 512 + h * 64 + slot * 8) = vv;
  }
}

// ---------------- external query attention (j==1 keys), 256 threads ----------------
__global__ __launch_bounds__(256) void k_ext_attn(
    const unsigned short* __restrict__ QKV, const float* __restrict__ EQKV,
    float* __restrict__ extpre) {
  int b = blockIdx.x >> 3, h = blockIdx.x & 7;
  int tid = threadIdx.x, lane = tid & 63, wv = tid >> 6;
  __shared__ float qs[64];
  __shared__ float ps[257];
  __shared__ float red[8];
  __shared__ float acc4[4][64];
  if (tid < 64) qs[tid] = EQKV[b * 1536 + h * 64 + tid];
  __syncthreads();
  const size_t base = (size_t)b * 2048 + 256;  // rows of chunk j=1
  float sc[2] = {-1e30f, -1e30f};
  #pragma unroll
  for (int it = 0; it < 2; ++it) {
    int key = tid + it * 256;
    if (key < 257) {
      float s = 0.f;
      if (key == 0) {
        const float* kr = EQKV + b * 1536 + 512 + h * 64;
        #pragma unroll 8
        for (int d = 0; d < 64; ++d) s += qs[d] * kr[d];
      } else {
        const unsigned short* kr = QKV + (base + key - 1) * 1536 + 512 + h * 64;
        #pragma unroll
        for (int c = 0; c < 8; ++c) {
          ush8 kv = *(const ush8*)(kr + c * 8);
          #pragma unroll
          for (int u = 0; u < 8; ++u) s += qs[c * 8 + u] * bf2f(kv[u]);
        }
      }
      sc[it] = s;
    }
  }
  float lmax = fmaxf(sc[0], sc[1]);
  for (int d = 1; d < 64; d <<= 1) lmax = fmaxf(lmax, __shfl_xor(lmax, d, 64));
  if (lane == 0) red[wv] = lmax;
  __syncthreads();
  float M = fmaxf(fmaxf(red[0], red[1]), fmaxf(red[2], red[3]));
  float lsum = 0.f;
  #pragma unroll
  for (int it = 0; it < 2; ++it) {
    int key = tid + it * 256;
    if (key < 257) { float p = __expf(sc[it] - M); ps[key] = p; lsum += p; }
  }
  for (int d = 1; d < 64; d <<= 1) lsum += __shfl_xor(lsum, d, 64);
  if (lane == 0) red[4 + wv] = lsum;
  __syncthreads();
  float S = red[4] + red[5] + red[6] + red[7];
  int d = tid & 63, part = tid >> 6;
  float acc = 0.f;
  for (int key = part; key < 257; key += 4) {
    float vv = (key == 0) ? EQKV[b * 1536 + 1024 + h * 64 + d]
                          : bf2f(QKV[(base + key - 1) * 1536 + 1024 + h * 64 + d]);
    acc += ps[key] * vv;
  }
  acc4[part][d] = acc;
  __syncthreads();
  if (tid < 64) {
    float r = (acc4[0][tid] + acc4[1][tid] + acc4[2][tid] + acc4[3][tid]) / S;
    extpre[b * 512 + h * 64 + tid] = r;
  }
}

// ---------------- external output projection: ext_pre[16][512] @ Wo + bo (fp32) ----------------
__global__ __launch_bounds__(256) void k_ext_out(
    const float* __restrict__ extpre, const float* __restrict__ Wo,
    const float* __restrict__ bo, float* __restrict__ out) {
  int b = blockIdx.x, half = blockIdx.y;
  int n = half * 256 + threadIdx.x;
  __shared__ float xs[512];
  xs[threadIdx.x] = extpre[b * 512 + threadIdx.x];
  xs[256 + threadIdx.x] = extpre[b * 512 + 256 + threadIdx.x];
  __syncthreads();
  float acc = bo[n];
  #pragma unroll 8
  for (int k = 0; k < 512; ++k) acc += xs[k] * Wo[k * 512 + n];
  out[16777216 + b * 512 + n] = acc;
}

extern "C" void kernel_launch(void* const* d_in, const int* in_sizes, int n_in,
                              void* d_out, int out_size, void* d_ws, size_t ws_size,
                              hipStream_t stream) {
  (void)in_sizes; (void)n_in; (void)out_size; (void)ws_size;
  const float* x   = (const float*)d_in[0];
  const float* ext = (const float*)d_in[1];
  const float* Wq  = (const float*)d_in[2];
  const float* bq  = (const float*)d_in[3];
  const float* Wk  = (const float*)d_in[4];
  const float* bk  = (const float*)d_in[5];
  const float* Wv  = (const float*)d_in[6];
  const float* bv  = (const float*)d_in[7];
  const float* Wo  = (const float*)d_in[8];
  const float* bo  = (const float*)d_in[9];
  float* out = (float*)d_out;

  char* ws = (char*)d_ws;
  size_t off = 0;
  auto take = [&](size_t bytes) { char* p = ws + off; off += (bytes + 255) & ~(size_t)255; return p; };
  unsigned short* Xbf    = (unsigned short*)take((size_t)32768 * 512 * 2);
  unsigned short* Wqkvt  = (unsigned short*)take((size_t)1536 * 512 * 2);
  unsigned short* Wot    = (unsigned short*)take((size_t)512 * 512 * 2);
  float*          biasqkv= (float*)take(1536 * 4);
  float*          EQKV   = (float*)take(16 * 1536 * 4);
  unsigned short* QKVb   = (unsigned short*)take((size_t)32768 * 1536 * 2);
  unsigned short* mainb  = (unsigned short*)take((size_t)32768 * 512 * 2);
  float*          extpre = (float*)take(16 * 512 * 4);

  k_conv_x<<<16384, 256, 0, stream>>>(x, Xbf);
  k_conv_w<<<3072, 256, 0, stream>>>(Wq, Wk, Wv, Wo, bq, bk, bv, Wqkvt, Wot, biasqkv);
  k_ext_qkv<<<96, 256, 0, stream>>>(ext, Wq, Wk, Wv, bq, bk, bv, EQKV);
  k_gemm<0><<<3072, 256, 0, stream>>>(Xbf, Wqkvt, biasqkv, QKVb, 1536, 12);  // 256 bm x 12 bn
  k_attn<<<1024, 512, 0, stream>>>(QKVb, EQKV, mainb);
  k_ext_attn<<<128, 256, 0, stream>>>(QKVb, EQKV, extpre);
  k_gemm<1><<<1024, 256, 0, stream>>>(mainb, Wot, bo, out, 512, 4);          // 256 bm x 4 bn
  k_ext_out<<<dim3(16, 2), 256, 0, stream>>>(extpre, Wo, bo, out);
}